// Round 2
// 76.887 us; speedup vs baseline: 1.0113x; 1.0113x over previous
//
#include <hip/hip_runtime.h>
#include <math.h>

#define BB 64
#define CC 32
#define DD 256
#define TEMP 0.1f
#define EPSC 1e-8f

typedef const __attribute__((address_space(1))) unsigned int* gptr_u32;
typedef __attribute__((address_space(3))) unsigned int* lptr_u32;

__device__ __forceinline__ float wave_reduce_sum(float v) {
    #pragma unroll
    for (int off = 32; off > 0; off >>= 1)
        v += __shfl_down(v, off, 64);
    return v;
}

// R7 == R6 resubmit (R6 bench died at container level before running; no
// counter evidence of a kernel defect on re-audit).
// R6: occupancy + VALU-cut rework of the R3 structure.
//  - grid (m=64, chunk=8), block = 512 threads (8 waves). LDS = 64 KB + 256 B
//    -> 2 blocks/CU -> 16 waves/CU = 4 waves/SIMD (was 2) for latency hiding.
//  - Each wave owns ONE anchor i = chunk*8 + wave; streams anchor row from L2
//    (float4, coalesced) against LDS-gathered rows of js[m] / is[m].
//  - njj/nkk are no longer accumulated in the dot loop: after staging, the
//    8 waves build ssn[64] = per-row sumsq of the staged 64 rows (once per
//    block), and each (m,i) reconstructs njj = sum_c ssn[pj[c]] with a 32-lane
//    table gather + half-wave reduce. Inner loop drops 20 -> 12 FMAs/c and
//    5 -> 3 shfl-reduction chains.
// NOTE (R4/R5 post-mortem): fusing the final LSE into this kernel via
// last-block-done + device fences measured 7-10 us SLOWER than the separate
// tiny loss kernel — keep the two-kernel structure.
__global__ __launch_bounds__(512, 4) void sim_part_kernel(
        const float* __restrict__ xis,
        const float* __restrict__ xjs,
        const int* __restrict__ idxj,
        const int* __restrict__ idxk,
        float* __restrict__ pos,    // [B]
        float* __restrict__ part)   // [B*B], [m][i]
{
    __shared__ float sj[CC * DD];   // js[m]  (32 KB)
    __shared__ float sk[CC * DD];   // is[m]  (32 KB)
    __shared__ float ssn[2 * CC];   // row sumsq: [0..31]=js rows, [32..63]=is rows

    const int m = blockIdx.x;
    const int lane = threadIdx.x & 63;
    const int wave = __builtin_amdgcn_readfirstlane(threadIdx.x >> 6);

    // ---- stage js[m], is[m] into LDS (16B global_load_lds, lane-contiguous) ----
    {
        const float* gj = xjs + (size_t)m * CC * DD;
        const float* gi = xis + (size_t)m * CC * DD;
        #pragma unroll
        for (int k = 0; k < 4; ++k) {
            const int off = (threadIdx.x + k * 512) * 4;   // float index, 16B/lane
            __builtin_amdgcn_global_load_lds((gptr_u32)(gj + off), (lptr_u32)(sj + off), 16, 0, 0);
            __builtin_amdgcn_global_load_lds((gptr_u32)(gi + off), (lptr_u32)(sk + off), 16, 0, 0);
        }
    }
    __syncthreads();   // drains vmcnt (incl. global_load_lds) before LDS reads

    // ---- per-row sumsq table: 8 waves x 8 rows (rows 0..31 = sj, 32..63 = sk) ----
    #pragma unroll
    for (int t = 0; t < 8; ++t) {
        const int r = wave * 8 + t;                       // wave-uniform
        const float* base = (r < CC) ? (sj + r * DD) : (sk + (r - CC) * DD);
        const float4 v = ((const float4*)base)[lane];
        float s = v.x * v.x + v.y * v.y + v.z * v.z + v.w * v.w;
        s = wave_reduce_sum(s);
        if (lane == 0) ssn[r] = s;
    }
    __syncthreads();

    // ---- main gather-dot: one anchor per wave ----
    const int i = blockIdx.y * 8 + wave;
    const bool diag = (i == m);
    const int* __restrict__ pj = idxj + ((size_t)i * BB + m) * CC;  // wave-uniform -> s_load
    const int* __restrict__ pk = idxk + ((size_t)i * BB + m) * CC;
    const float4* a4 = (const float4*)(xis + (size_t)i * CC * DD);

    float dj = 0.f, dk = 0.f, naa = 0.f;
    #pragma unroll 4
    for (int c = 0; c < CC; ++c) {
        const int ij = diag ? c : pj[c];
        const int ik = diag ? c : pk[c];
        const float4 a  = a4[c * (DD / 4) + lane];
        const float4 jv = ((const float4*)(sj + ij * DD))[lane];
        const float4 kv = ((const float4*)(sk + ik * DD))[lane];
        dj  += a.x * jv.x + a.y * jv.y + a.z * jv.z + a.w * jv.w;
        dk  += a.x * kv.x + a.y * kv.y + a.z * kv.z + a.w * kv.w;
        naa += a.x * a.x  + a.y * a.y  + a.z * a.z  + a.w * a.w;
    }
    // interleaved 3-chain butterfly reduce
    #pragma unroll
    for (int off = 32; off > 0; off >>= 1) {
        dj  += __shfl_down(dj,  off, 64);
        dk  += __shfl_down(dk,  off, 64);
        naa += __shfl_down(naa, off, 64);
    }

    // ---- gathered norms from the sumsq table ----
    // lanes 0..31: njj contribution ssn[pj[l]]; lanes 32..63: nkk via ssn[32+pk[l]]
    const int l2 = lane & 31;
    int row;
    if (diag) {
        row = l2;
    } else {
        const int* pb = (lane < 32) ? pj : pk;
        row = pb[l2];
    }
    float nv = ssn[(lane < 32 ? 0 : CC) + row];
    #pragma unroll
    for (int off = 16; off > 0; off >>= 1)
        nv += __shfl_down(nv, off, 64);   // offsets <32 keep the two halves separate
    const float njj = __shfl(nv, 0, 64);
    const float nkk = __shfl(nv, 32, 64);

    if (lane == 0) {
        const float ni = sqrtf(naa);
        if (diag) {
            pos[i] = dj / fmaxf(ni * sqrtf(njj), EPSC) / TEMP;
            part[m * BB + i] = 0.0f;
        } else {
            const float s1 = dj / fmaxf(ni * sqrtf(njj), EPSC) / TEMP;
            const float s2 = dk / fmaxf(ni * sqrtf(nkk), EPSC) / TEMP;
            // logits are cos/0.1 in [-10,10]: fixed shift 10 is exact
            part[m * BB + i] = expf(s1 - 10.0f) + expf(s2 - 10.0f);
        }
    }
}

// Loss: lse_i = 10 + log(sum_m part[m][i] + exp(pos_i - 10));
// loss = sum_i (lse_i - pos_i) / (2B). 1 block x 256 threads; thread (q,i)
// sums m = q*16..q*16+15 (reads part[m*64+i]: lane-contiguous, coalesced).
__global__ __launch_bounds__(256) void loss_kernel(
        const float* __restrict__ pos,
        const float* __restrict__ part,
        float* __restrict__ out)
{
    __shared__ float sp[4][BB];
    const int t = threadIdx.x;
    const int i = t & 63;
    const int q = t >> 6;

    float s = 0.f;
    #pragma unroll
    for (int mm = 0; mm < 16; ++mm)
        s += part[(q * 16 + mm) * BB + i];
    sp[q][i] = s;
    __syncthreads();

    if (t < 64) {
        const float p = pos[i];
        const float tot = sp[0][i] + sp[1][i] + sp[2][i] + sp[3][i] + expf(p - 10.0f);
        float v = 10.0f + logf(tot) - p;
        v = wave_reduce_sum(v);
        if (i == 0) out[0] = v * (1.0f / (2.0f * BB));
    }
}

extern "C" void kernel_launch(void* const* d_in, const int* in_sizes, int n_in,
                              void* d_out, int out_size, void* d_ws, size_t ws_size,
                              hipStream_t stream) {
    const float* xis  = (const float*)d_in[0];  // children_is [B,C,D] f32
    const float* xjs  = (const float*)d_in[1];  // children_js [B,C,D] f32
    const int*   idxj = (const int*)d_in[2];    // neg_idx_j [B,B,C] i32
    const int*   idxk = (const int*)d_in[3];    // neg_idx_k [B,B,C] i32
    // d_in[4] = partnet_ids (unused; reference masks via eye())
    float* out = (float*)d_out;

    float* ws   = (float*)d_ws;
    float* pos  = ws;               // 64 floats
    float* part = pos + BB;         // 4096 floats, [m][i]

    sim_part_kernel<<<dim3(BB, 8), 512, 0, stream>>>(xis, xjs, idxj, idxk, pos, part);
    loss_kernel<<<1, 256, 0, stream>>>(pos, part, out);
}